// Round 1
// baseline (1213.188 us; speedup 1.0000x reference)
//
#include <hip/hip_runtime.h>
#include <hip/hip_bf16.h>
#include <stdint.h>

// Problem constants
#define T_TOK 8192      // B*S tokens
#define DMODEL 1024
#define FFDIM 4096
#define NEXP 8
#define TOPK 2
#define MTILES 136              // ceil-padded row tiles: 16384 + 8*127 <= 136*128
#define ROWS_PAD (MTILES * 128) // 17408

typedef __bf16 bf16x8 __attribute__((ext_vector_type(8)));
typedef float f32x4 __attribute__((ext_vector_type(4)));

__device__ __forceinline__ unsigned short f2bf(float f) {
    union { float f; unsigned u; } v; v.f = f;
    unsigned u = v.u;
    u += 0x7fffu + ((u >> 16) & 1u);   // round-to-nearest-even
    return (unsigned short)(u >> 16);
}

// ---------------- init: zero out region, row_token=-1, zero_row, counters ----
__global__ void init_kernel(float* __restrict__ out0, int* __restrict__ row_token,
                            unsigned short* __restrict__ zero_row, int* __restrict__ cnt_fill) {
    size_t i = (size_t)blockIdx.x * blockDim.x + threadIdx.x;
    if (i < (size_t)T_TOK * DMODEL) out0[i] = 0.f;
    if (i < ROWS_PAD) row_token[i] = -1;
    if (i < DMODEL) zero_row[i] = 0;
    if (i < 16) cnt_fill[i] = 0;
}

// ---------------- fp32 -> bf16 conversion (vectorized) -----------------------
__global__ void cvt_kernel(const float* __restrict__ src, unsigned short* __restrict__ dst, int n4) {
    int i = blockIdx.x * blockDim.x + threadIdx.x;
    if (i < n4) {
        float4 v = ((const float4*)src)[i];
        ushort4 o;
        o.x = f2bf(v.x); o.y = f2bf(v.y); o.z = f2bf(v.z); o.w = f2bf(v.w);
        ((ushort4*)dst)[i] = o;
    }
}

// ---------------- gating: one wave per token, fp64 accumulation --------------
__global__ __launch_bounds__(256)
void gate_kernel(const float* __restrict__ x, const float* __restrict__ wg,
                 const float* __restrict__ bg,
                 float* __restrict__ out_idx, float* __restrict__ out_val,
                 int* __restrict__ tok_e, float* __restrict__ tok_g, int* __restrict__ cnt) {
    int t = blockIdx.x * 4 + (threadIdx.x >> 6);
    int lane = threadIdx.x & 63;
    const float4* xr = (const float4*)(x + (size_t)t * DMODEL);
    double acc[NEXP];
#pragma unroll
    for (int e = 0; e < NEXP; ++e) acc[e] = 0.0;
#pragma unroll
    for (int it = 0; it < 4; ++it) {
        float4 xv = xr[lane + it * 64];
#pragma unroll
        for (int e = 0; e < NEXP; ++e) {
            float4 wv = ((const float4*)(wg + e * DMODEL))[lane + it * 64];
            acc[e] += (double)xv.x * wv.x + (double)xv.y * wv.y +
                      (double)xv.z * wv.z + (double)xv.w * wv.w;
        }
    }
#pragma unroll
    for (int off = 32; off; off >>= 1)
#pragma unroll
        for (int e = 0; e < NEXP; ++e) acc[e] += __shfl_down(acc[e], off, 64);
    if (lane == 0) {
        double lg[NEXP], mx = -1e300;
#pragma unroll
        for (int e = 0; e < NEXP; ++e) { lg[e] = acc[e] + (double)bg[e]; mx = lg[e] > mx ? lg[e] : mx; }
        double p[NEXP], s = 0.0;
#pragma unroll
        for (int e = 0; e < NEXP; ++e) { p[e] = exp(lg[e] - mx); s += p[e]; }
#pragma unroll
        for (int e = 0; e < NEXP; ++e) p[e] /= s;
        int i0 = 0;
#pragma unroll
        for (int e = 1; e < NEXP; ++e) if (p[e] > p[i0]) i0 = e;
        int i1 = (i0 == 0) ? 1 : 0;
#pragma unroll
        for (int e = 0; e < NEXP; ++e) if (e != i0 && p[e] > p[i1]) i1 = e;
        out_idx[t * 2 + 0] = (float)i0;
        out_idx[t * 2 + 1] = (float)i1;
        out_val[t * 2 + 0] = (float)p[i0];
        out_val[t * 2 + 1] = (float)p[i1];
        tok_e[t * 2 + 0] = i0; tok_e[t * 2 + 1] = i1;
        tok_g[t * 2 + 0] = (float)p[i0]; tok_g[t * 2 + 1] = (float)p[i1];
        atomicAdd(&cnt[i0], 1);
        atomicAdd(&cnt[i1], 1);
    }
}

// ---------------- 128-padded segment offsets ---------------------------------
__global__ void offsets_kernel(const int* __restrict__ cnt, int* __restrict__ off_pad) {
    if (threadIdx.x == 0 && blockIdx.x == 0) {
        int o = 0;
        off_pad[0] = 0;
#pragma unroll
        for (int e = 0; e < NEXP; ++e) {
            o += ((cnt[e] + 127) >> 7) << 7;
            off_pad[e + 1] = o;
        }
    }
}

// ---------------- scatter tokens into padded row space -----------------------
__global__ void scatter_kernel(const int* __restrict__ tok_e, const float* __restrict__ tok_g,
                               const int* __restrict__ off_pad, int* __restrict__ fill,
                               int* __restrict__ row_token, float* __restrict__ row_gate) {
    int i = blockIdx.x * blockDim.x + threadIdx.x;
    if (i < T_TOK * TOPK) {
        int e = tok_e[i];
        int pos = off_pad[e] + atomicAdd(&fill[e], 1);
        row_token[pos] = i >> 1;
        row_gate[pos] = tok_g[i];
    }
}

// ---------------- grouped GEMM (m97 structure): C = A * W^T ------------------
// MODE 0: A = gathered x_bf16 rows, store h = leakyrelu(C + b1) as bf16
// MODE 1: A = h rows, atomicAdd gate*(C + b2) into out
template <int MODE, int KD, int ND>
__global__ __launch_bounds__(256)
void moe_gemm(const unsigned short* __restrict__ A, const unsigned short* __restrict__ W,
              const float* __restrict__ bias, const int* __restrict__ row_token,
              const float* __restrict__ row_gate, const int* __restrict__ off_pad,
              const unsigned short* __restrict__ zero_row,
              unsigned short* __restrict__ Hout, float* __restrict__ Out) {
    __shared__ unsigned short As[128 * 64];
    __shared__ unsigned short Bs[128 * 64];
    const int m0 = blockIdx.x * 128;
    const int n0 = blockIdx.y * 128;
    // expert for this row tile (off_pad monotone; last true wins)
    int e = 0;
#pragma unroll
    for (int q = 0; q < NEXP - 1; ++q)
        if (off_pad[q + 1] <= m0) e = q + 1;

    const int tid = threadIdx.x;
    const int wave = tid >> 6;
    const int lane = tid & 63;
    const int wm = wave >> 1, wn = wave & 1;
    const int col8 = tid & 7;      // 16B chunk within a 64-elem row
    const int lane15 = lane & 15;
    const int quad = lane >> 4;

    // staging source pointers (4 rounds of 256 x 16B chunks per tile)
    const unsigned short* aptr[4];
    const unsigned short* bptr[4];
#pragma unroll
    for (int r = 0; r < 4; ++r) {
        int c = r * 256 + tid;
        int row = c >> 3;
        const unsigned short* ab;
        if (MODE == 0) {
            int tok = row_token[m0 + row];
            ab = (tok < 0) ? zero_row : (A + (size_t)tok * KD);
        } else {
            ab = A + (size_t)(m0 + row) * KD;
        }
        aptr[r] = ab + col8 * 8;
        bptr[r] = W + ((size_t)e * ND + (size_t)(n0 + row)) * (size_t)KD + col8 * 8;
    }

    f32x4 acc[4][4];
#pragma unroll
    for (int i = 0; i < 4; ++i)
#pragma unroll
        for (int j = 0; j < 4; ++j) acc[i][j] = (f32x4)0.f;

    const int ldsAoff = (wm * 64 + lane15) * 64 + quad * 8;
    const int ldsBoff = (wn * 64 + lane15) * 64 + quad * 8;

    for (int k0 = 0; k0 < KD; k0 += 64) {
#pragma unroll
        for (int r = 0; r < 4; ++r)
            __builtin_amdgcn_global_load_lds(
                (const __attribute__((address_space(1))) void*)(aptr[r] + k0),
                (__attribute__((address_space(3))) void*)(As + (r * 256 + wave * 64) * 8),
                16, 0, 0);
#pragma unroll
        for (int r = 0; r < 4; ++r)
            __builtin_amdgcn_global_load_lds(
                (const __attribute__((address_space(1))) void*)(bptr[r] + k0),
                (__attribute__((address_space(3))) void*)(Bs + (r * 256 + wave * 64) * 8),
                16, 0, 0);
        __syncthreads();
#pragma unroll
        for (int ks = 0; ks < 64; ks += 32) {
            bf16x8 af[4], bfv[4];
#pragma unroll
            for (int i = 0; i < 4; ++i)
                af[i] = *(const bf16x8*)(As + ldsAoff + i * 16 * 64 + ks);
#pragma unroll
            for (int j = 0; j < 4; ++j)
                bfv[j] = *(const bf16x8*)(Bs + ldsBoff + j * 16 * 64 + ks);
#pragma unroll
            for (int i = 0; i < 4; ++i)
#pragma unroll
                for (int j = 0; j < 4; ++j)
                    acc[i][j] = __builtin_amdgcn_mfma_f32_16x16x32_bf16(af[i], bfv[j], acc[i][j], 0, 0, 0);
        }
        __syncthreads();
    }

    // epilogue
#pragma unroll
    for (int i = 0; i < 4; ++i) {
#pragma unroll
        for (int r4 = 0; r4 < 4; ++r4) {
            int m = m0 + wm * 64 + i * 16 + quad * 4 + r4;
            int tok = 0; float g = 0.f;
            if (MODE == 1) { tok = row_token[m]; g = row_gate[m]; }
#pragma unroll
            for (int j = 0; j < 4; ++j) {
                int n = n0 + wn * 64 + j * 16 + lane15;
                float v = acc[i][j][r4] + bias[e * ND + n];
                if (MODE == 0) {
                    v = v > 0.f ? v : 0.1f * v;
                    Hout[(size_t)m * ND + n] = f2bf(v);
                } else {
                    if (tok >= 0) atomicAdd(Out + (size_t)tok * ND + n, g * v);
                }
            }
        }
    }
}

extern "C" void kernel_launch(void* const* d_in, const int* in_sizes, int n_in,
                              void* d_out, int out_size, void* d_ws, size_t ws_size,
                              hipStream_t stream) {
    const float* x  = (const float*)d_in[0];
    const float* wg = (const float*)d_in[1];
    const float* bg = (const float*)d_in[2];
    const float* w1 = (const float*)d_in[3];
    const float* b1 = (const float*)d_in[4];
    const float* w2 = (const float*)d_in[5];
    const float* b2 = (const float*)d_in[6];
    float* out0 = (float*)d_out;
    float* out_idx = out0 + (size_t)T_TOK * DMODEL;
    float* out_val = out_idx + T_TOK * TOPK;

    char* p = (char*)d_ws;
    auto alloc = [&](size_t bytes) {
        char* q = p;
        p += (bytes + 255) & ~(size_t)255;
        return q;
    };
    unsigned short* xb  = (unsigned short*)alloc((size_t)T_TOK * DMODEL * 2);
    unsigned short* w1b = (unsigned short*)alloc((size_t)NEXP * FFDIM * DMODEL * 2);
    unsigned short* w2b = (unsigned short*)alloc((size_t)NEXP * DMODEL * FFDIM * 2);
    unsigned short* hb  = (unsigned short*)alloc((size_t)ROWS_PAD * FFDIM * 2);
    unsigned short* zrow = (unsigned short*)alloc(DMODEL * 2);
    int* cnt = (int*)alloc(64);   // cnt[8] + fill[8]
    int* fill = cnt + 8;
    int* off_pad = (int*)alloc(64);
    int* tok_e = (int*)alloc((size_t)T_TOK * TOPK * 4);
    float* tok_g = (float*)alloc((size_t)T_TOK * TOPK * 4);
    int* row_token = (int*)alloc((size_t)ROWS_PAD * 4);
    float* row_gate = (float*)alloc((size_t)ROWS_PAD * 4);
    if ((size_t)(p - (char*)d_ws) > ws_size) return;  // ws too small: fail visibly, no OOB

    init_kernel<<<(T_TOK * DMODEL + 255) / 256, 256, 0, stream>>>(out0, row_token, zrow, cnt);
    cvt_kernel<<<(T_TOK * DMODEL / 4 + 255) / 256, 256, 0, stream>>>(x, xb, T_TOK * DMODEL / 4);
    cvt_kernel<<<(NEXP * FFDIM * DMODEL / 4 + 255) / 256, 256, 0, stream>>>(w1, w1b, NEXP * FFDIM * DMODEL / 4);
    cvt_kernel<<<(NEXP * DMODEL * FFDIM / 4 + 255) / 256, 256, 0, stream>>>(w2, w2b, NEXP * DMODEL * FFDIM / 4);
    gate_kernel<<<T_TOK / 4, 256, 0, stream>>>(x, wg, bg, out_idx, out_val, tok_e, tok_g, cnt);
    offsets_kernel<<<1, 64, 0, stream>>>(cnt, off_pad);
    scatter_kernel<<<(T_TOK * TOPK + 255) / 256, 256, 0, stream>>>(tok_e, tok_g, off_pad, fill, row_token, row_gate);
    moe_gemm<0, DMODEL, FFDIM><<<dim3(MTILES, FFDIM / 128), 256, 0, stream>>>(
        xb, w1b, b1, row_token, row_gate, off_pad, zrow, hb, nullptr);
    moe_gemm<1, FFDIM, DMODEL><<<dim3(MTILES, DMODEL / 128), 256, 0, stream>>>(
        hb, w2b, b2, row_token, row_gate, off_pad, zrow, nullptr, out0);
}

// Round 2
// 1156.887 us; speedup vs baseline: 1.0487x; 1.0487x over previous
//
#include <hip/hip_runtime.h>
#include <hip/hip_bf16.h>
#include <stdint.h>

// Problem constants
#define T_TOK 8192      // B*S tokens
#define DMODEL 1024
#define FFDIM 4096
#define NEXP 8
#define TOPK 2
#define MTILES 136              // ceil-padded row tiles: 16384 + 8*127 <= 136*128
#define ROWS_PAD (MTILES * 128) // 17408

typedef __bf16 bf16x8 __attribute__((ext_vector_type(8)));
typedef float f32x4 __attribute__((ext_vector_type(4)));

__device__ __forceinline__ unsigned short f2bf(float f) {
    union { float f; unsigned u; } v; v.f = f;
    unsigned u = v.u;
    u += 0x7fffu + ((u >> 16) & 1u);   // round-to-nearest-even
    return (unsigned short)(u >> 16);
}

// ---------------- init: zero out region, row_token=-1, zero_row, counters ----
__global__ void init_kernel(float* __restrict__ out0, int* __restrict__ row_token,
                            unsigned short* __restrict__ zero_row, int* __restrict__ cnt_fill) {
    size_t i = (size_t)blockIdx.x * blockDim.x + threadIdx.x;
    if (i < (size_t)T_TOK * DMODEL) out0[i] = 0.f;
    if (i < ROWS_PAD) row_token[i] = -1;
    if (i < DMODEL) zero_row[i] = 0;
    if (i < 16) cnt_fill[i] = 0;
}

// ---------------- fp32 -> bf16 conversion (vectorized) -----------------------
__global__ void cvt_kernel(const float* __restrict__ src, unsigned short* __restrict__ dst, int n4) {
    int i = blockIdx.x * blockDim.x + threadIdx.x;
    if (i < n4) {
        float4 v = ((const float4*)src)[i];
        ushort4 o;
        o.x = f2bf(v.x); o.y = f2bf(v.y); o.z = f2bf(v.z); o.w = f2bf(v.w);
        ((ushort4*)dst)[i] = o;
    }
}

// ---------------- gating: one wave per token, fp64 accumulation --------------
__global__ __launch_bounds__(256)
void gate_kernel(const float* __restrict__ x, const float* __restrict__ wg,
                 const float* __restrict__ bg,
                 float* __restrict__ out_idx, float* __restrict__ out_val,
                 int* __restrict__ tok_e, float* __restrict__ tok_g, int* __restrict__ cnt) {
    int t = blockIdx.x * 4 + (threadIdx.x >> 6);
    int lane = threadIdx.x & 63;
    const float4* xr = (const float4*)(x + (size_t)t * DMODEL);
    double acc[NEXP];
#pragma unroll
    for (int e = 0; e < NEXP; ++e) acc[e] = 0.0;
#pragma unroll
    for (int it = 0; it < 4; ++it) {
        float4 xv = xr[lane + it * 64];
#pragma unroll
        for (int e = 0; e < NEXP; ++e) {
            float4 wv = ((const float4*)(wg + e * DMODEL))[lane + it * 64];
            acc[e] += (double)xv.x * wv.x + (double)xv.y * wv.y +
                      (double)xv.z * wv.z + (double)xv.w * wv.w;
        }
    }
#pragma unroll
    for (int off = 32; off; off >>= 1)
#pragma unroll
        for (int e = 0; e < NEXP; ++e) acc[e] += __shfl_down(acc[e], off, 64);
    if (lane == 0) {
        double lg[NEXP], mx = -1e300;
#pragma unroll
        for (int e = 0; e < NEXP; ++e) { lg[e] = acc[e] + (double)bg[e]; mx = lg[e] > mx ? lg[e] : mx; }
        double p[NEXP], s = 0.0;
#pragma unroll
        for (int e = 0; e < NEXP; ++e) { p[e] = exp(lg[e] - mx); s += p[e]; }
#pragma unroll
        for (int e = 0; e < NEXP; ++e) p[e] /= s;
        int i0 = 0;
#pragma unroll
        for (int e = 1; e < NEXP; ++e) if (p[e] > p[i0]) i0 = e;
        int i1 = (i0 == 0) ? 1 : 0;
#pragma unroll
        for (int e = 0; e < NEXP; ++e) if (e != i0 && p[e] > p[i1]) i1 = e;
        out_idx[t * 2 + 0] = (float)i0;
        out_idx[t * 2 + 1] = (float)i1;
        out_val[t * 2 + 0] = (float)p[i0];
        out_val[t * 2 + 1] = (float)p[i1];
        tok_e[t * 2 + 0] = i0; tok_e[t * 2 + 1] = i1;
        tok_g[t * 2 + 0] = (float)p[i0]; tok_g[t * 2 + 1] = (float)p[i1];
        atomicAdd(&cnt[i0], 1);
        atomicAdd(&cnt[i1], 1);
    }
}

// ---------------- 128-padded segment offsets ---------------------------------
__global__ void offsets_kernel(const int* __restrict__ cnt, int* __restrict__ off_pad) {
    if (threadIdx.x == 0 && blockIdx.x == 0) {
        int o = 0;
        off_pad[0] = 0;
#pragma unroll
        for (int e = 0; e < NEXP; ++e) {
            o += ((cnt[e] + 127) >> 7) << 7;
            off_pad[e + 1] = o;
        }
    }
}

// ---------------- scatter tokens into padded row space -----------------------
__global__ void scatter_kernel(const int* __restrict__ tok_e, const float* __restrict__ tok_g,
                               const int* __restrict__ off_pad, int* __restrict__ fill,
                               int* __restrict__ row_token, float* __restrict__ row_gate) {
    int i = blockIdx.x * blockDim.x + threadIdx.x;
    if (i < T_TOK * TOPK) {
        int e = tok_e[i];
        int pos = off_pad[e] + atomicAdd(&fill[e], 1);
        row_token[pos] = i >> 1;
        row_gate[pos] = tok_g[i];
    }
}

// ---------------- grouped GEMM (m97 structure + XOR swizzle): C = A * W^T ----
// LDS layout: [row][chunk] where physical chunk = logical chunk ^ (row & 7).
// Swizzle applied at the global-source side (global_load_lds dest is pinned to
// lane order), un-applied at ds_read time. Breaks the 128B-stride 16-way bank
// conflict (5.35e7 conflict cycles measured in R1) down to free 2-way.
// MODE 0: A = gathered x_bf16 rows, store h = leakyrelu(C + b1) as bf16
// MODE 1: A = h rows, atomicAdd gate*(C + b2) into out
template <int MODE, int KD, int ND>
__global__ __launch_bounds__(256)
void moe_gemm(const unsigned short* __restrict__ A, const unsigned short* __restrict__ W,
              const float* __restrict__ bias, const int* __restrict__ row_token,
              const float* __restrict__ row_gate, const int* __restrict__ off_pad,
              const unsigned short* __restrict__ zero_row,
              unsigned short* __restrict__ Hout, float* __restrict__ Out) {
    __shared__ unsigned short As[128 * 64];
    __shared__ unsigned short Bs[128 * 64];
    const int m0 = blockIdx.x * 128;
    const int n0 = blockIdx.y * 128;
    // expert for this row tile (off_pad monotone; last true wins)
    int e = 0;
#pragma unroll
    for (int q = 0; q < NEXP - 1; ++q)
        if (off_pad[q + 1] <= m0) e = q + 1;

    const int tid = threadIdx.x;
    const int wave = tid >> 6;
    const int lane = tid & 63;
    const int wm = wave >> 1, wn = wave & 1;
    const int col8 = tid & 7;              // 16B chunk within a 64-elem row
    const int stg_swz = (tid >> 3) & 7;    // = row&7 for every staging round
    const int scol = (col8 ^ stg_swz);     // swizzled source chunk
    const int lane15 = lane & 15;
    const int quad = lane >> 2 >> 2;       // lane >> 4
    const int rd_swz = lane15 & 7;         // = row&7 for fragment reads

    // staging source pointers (4 rounds of 256 x 16B chunks per tile)
    const unsigned short* aptr[4];
    const unsigned short* bptr[4];
#pragma unroll
    for (int r = 0; r < 4; ++r) {
        int c = r * 256 + tid;
        int row = c >> 3;
        const unsigned short* ab;
        if (MODE == 0) {
            int tok = row_token[m0 + row];
            ab = (tok < 0) ? zero_row : (A + (size_t)tok * KD);
        } else {
            ab = A + (size_t)(m0 + row) * KD;
        }
        aptr[r] = ab + scol * 8;
        bptr[r] = W + ((size_t)e * ND + (size_t)(n0 + row)) * (size_t)KD + scol * 8;
    }

    f32x4 acc[4][4];
#pragma unroll
    for (int i = 0; i < 4; ++i)
#pragma unroll
        for (int j = 0; j < 4; ++j) acc[i][j] = (f32x4)0.f;

    const int rowA = wm * 64 + lane15;     // + i*16 per fragment
    const int rowB = wn * 64 + lane15;     // + j*16 per fragment

    for (int k0 = 0; k0 < KD; k0 += 64) {
#pragma unroll
        for (int r = 0; r < 4; ++r)
            __builtin_amdgcn_global_load_lds(
                (const __attribute__((address_space(1))) void*)(aptr[r] + k0),
                (__attribute__((address_space(3))) void*)(As + (r * 256 + wave * 64) * 8),
                16, 0, 0);
#pragma unroll
        for (int r = 0; r < 4; ++r)
            __builtin_amdgcn_global_load_lds(
                (const __attribute__((address_space(1))) void*)(bptr[r] + k0),
                (__attribute__((address_space(3))) void*)(Bs + (r * 256 + wave * 64) * 8),
                16, 0, 0);
        __syncthreads();
#pragma unroll
        for (int ks = 0; ks < 64; ks += 32) {
            const int pc = ((ks >> 3) + quad) ^ rd_swz;   // physical chunk
            bf16x8 af[4], bfv[4];
#pragma unroll
            for (int i = 0; i < 4; ++i)
                af[i] = *(const bf16x8*)(As + (rowA + i * 16) * 64 + pc * 8);
#pragma unroll
            for (int j = 0; j < 4; ++j)
                bfv[j] = *(const bf16x8*)(Bs + (rowB + j * 16) * 64 + pc * 8);
#pragma unroll
            for (int i = 0; i < 4; ++i)
#pragma unroll
                for (int j = 0; j < 4; ++j)
                    acc[i][j] = __builtin_amdgcn_mfma_f32_16x16x32_bf16(af[i], bfv[j], acc[i][j], 0, 0, 0);
        }
        __syncthreads();
    }

    // epilogue
#pragma unroll
    for (int i = 0; i < 4; ++i) {
#pragma unroll
        for (int r4 = 0; r4 < 4; ++r4) {
            int m = m0 + wm * 64 + i * 16 + quad * 4 + r4;
            int tok = 0; float g = 0.f;
            if (MODE == 1) { tok = row_token[m]; g = row_gate[m]; }
#pragma unroll
            for (int j = 0; j < 4; ++j) {
                int n = n0 + wn * 64 + j * 16 + lane15;
                float v = acc[i][j][r4] + bias[e * ND + n];
                if (MODE == 0) {
                    v = v > 0.f ? v : 0.1f * v;
                    Hout[(size_t)m * ND + n] = f2bf(v);
                } else {
                    if (tok >= 0) atomicAdd(Out + (size_t)tok * ND + n, g * v);
                }
            }
        }
    }
}

extern "C" void kernel_launch(void* const* d_in, const int* in_sizes, int n_in,
                              void* d_out, int out_size, void* d_ws, size_t ws_size,
                              hipStream_t stream) {
    const float* x  = (const float*)d_in[0];
    const float* wg = (const float*)d_in[1];
    const float* bg = (const float*)d_in[2];
    const float* w1 = (const float*)d_in[3];
    const float* b1 = (const float*)d_in[4];
    const float* w2 = (const float*)d_in[5];
    const float* b2 = (const float*)d_in[6];
    float* out0 = (float*)d_out;
    float* out_idx = out0 + (size_t)T_TOK * DMODEL;
    float* out_val = out_idx + T_TOK * TOPK;

    char* p = (char*)d_ws;
    auto alloc = [&](size_t bytes) {
        char* q = p;
        p += (bytes + 255) & ~(size_t)255;
        return q;
    };
    unsigned short* xb  = (unsigned short*)alloc((size_t)T_TOK * DMODEL * 2);
    unsigned short* w1b = (unsigned short*)alloc((size_t)NEXP * FFDIM * DMODEL * 2);
    unsigned short* w2b = (unsigned short*)alloc((size_t)NEXP * DMODEL * FFDIM * 2);
    unsigned short* hb  = (unsigned short*)alloc((size_t)ROWS_PAD * FFDIM * 2);
    unsigned short* zrow = (unsigned short*)alloc(DMODEL * 2);
    int* cnt = (int*)alloc(64);   // cnt[8] + fill[8]
    int* fill = cnt + 8;
    int* off_pad = (int*)alloc(64);
    int* tok_e = (int*)alloc((size_t)T_TOK * TOPK * 4);
    float* tok_g = (float*)alloc((size_t)T_TOK * TOPK * 4);
    int* row_token = (int*)alloc((size_t)ROWS_PAD * 4);
    float* row_gate = (float*)alloc((size_t)ROWS_PAD * 4);
    if ((size_t)(p - (char*)d_ws) > ws_size) return;  // ws too small: fail visibly, no OOB

    init_kernel<<<(T_TOK * DMODEL + 255) / 256, 256, 0, stream>>>(out0, row_token, zrow, cnt);
    cvt_kernel<<<(T_TOK * DMODEL / 4 + 255) / 256, 256, 0, stream>>>(x, xb, T_TOK * DMODEL / 4);
    cvt_kernel<<<(NEXP * FFDIM * DMODEL / 4 + 255) / 256, 256, 0, stream>>>(w1, w1b, NEXP * FFDIM * DMODEL / 4);
    cvt_kernel<<<(NEXP * DMODEL * FFDIM / 4 + 255) / 256, 256, 0, stream>>>(w2, w2b, NEXP * DMODEL * FFDIM / 4);
    gate_kernel<<<T_TOK / 4, 256, 0, stream>>>(x, wg, bg, out_idx, out_val, tok_e, tok_g, cnt);
    offsets_kernel<<<1, 64, 0, stream>>>(cnt, off_pad);
    scatter_kernel<<<(T_TOK * TOPK + 255) / 256, 256, 0, stream>>>(tok_e, tok_g, off_pad, fill, row_token, row_gate);
    moe_gemm<0, DMODEL, FFDIM><<<dim3(MTILES, FFDIM / 128), 256, 0, stream>>>(
        xb, w1b, b1, row_token, row_gate, off_pad, zrow, hb, nullptr);
    moe_gemm<1, FFDIM, DMODEL><<<dim3(MTILES, DMODEL / 128), 256, 0, stream>>>(
        hb, w2b, b2, row_token, row_gate, off_pad, zrow, nullptr, out0);
}

// Round 3
// 1077.527 us; speedup vs baseline: 1.1259x; 1.0736x over previous
//
#include <hip/hip_runtime.h>
#include <hip/hip_bf16.h>
#include <stdint.h>

// Problem constants
#define T_TOK 8192      // B*S tokens
#define DMODEL 1024
#define FFDIM 4096
#define NEXP 8
#define TOPK 2
#define MTILES 136              // ceil-padded row tiles: 16384 + 8*127 <= 136*128
#define ROWS_PAD (MTILES * 128) // 17408

typedef __bf16 bf16x8 __attribute__((ext_vector_type(8)));
typedef float f32x4 __attribute__((ext_vector_type(4)));

__device__ __forceinline__ unsigned short f2bf(float f) {
    union { float f; unsigned u; } v; v.f = f;
    unsigned u = v.u;
    u += 0x7fffu + ((u >> 16) & 1u);   // round-to-nearest-even
    return (unsigned short)(u >> 16);
}

// ---------------- init: zero out region, row_token=-1, zero_row, counters ----
__global__ void init_kernel(float* __restrict__ out0, int* __restrict__ row_token,
                            unsigned short* __restrict__ zero_row, int* __restrict__ cnt_fill) {
    size_t i = (size_t)blockIdx.x * blockDim.x + threadIdx.x;
    if (i < (size_t)T_TOK * DMODEL) out0[i] = 0.f;
    if (i < ROWS_PAD) row_token[i] = -1;
    if (i < DMODEL) zero_row[i] = 0;
    if (i < 16) cnt_fill[i] = 0;
}

// ---------------- fp32 -> bf16 conversion (vectorized) -----------------------
__global__ void cvt_kernel(const float* __restrict__ src, unsigned short* __restrict__ dst, int n4) {
    int i = blockIdx.x * blockDim.x + threadIdx.x;
    if (i < n4) {
        float4 v = ((const float4*)src)[i];
        ushort4 o;
        o.x = f2bf(v.x); o.y = f2bf(v.y); o.z = f2bf(v.z); o.w = f2bf(v.w);
        ((ushort4*)dst)[i] = o;
    }
}

// ---------------- gating: one wave per token, fp64 accumulation --------------
__global__ __launch_bounds__(256)
void gate_kernel(const float* __restrict__ x, const float* __restrict__ wg,
                 const float* __restrict__ bg,
                 float* __restrict__ out_idx, float* __restrict__ out_val,
                 int* __restrict__ tok_e, float* __restrict__ tok_g, int* __restrict__ cnt) {
    int t = blockIdx.x * 4 + (threadIdx.x >> 6);
    int lane = threadIdx.x & 63;
    const float4* xr = (const float4*)(x + (size_t)t * DMODEL);
    double acc[NEXP];
#pragma unroll
    for (int e = 0; e < NEXP; ++e) acc[e] = 0.0;
#pragma unroll
    for (int it = 0; it < 4; ++it) {
        float4 xv = xr[lane + it * 64];
#pragma unroll
        for (int e = 0; e < NEXP; ++e) {
            float4 wv = ((const float4*)(wg + e * DMODEL))[lane + it * 64];
            acc[e] += (double)xv.x * wv.x + (double)xv.y * wv.y +
                      (double)xv.z * wv.z + (double)xv.w * wv.w;
        }
    }
#pragma unroll
    for (int off = 32; off; off >>= 1)
#pragma unroll
        for (int e = 0; e < NEXP; ++e) acc[e] += __shfl_down(acc[e], off, 64);
    if (lane == 0) {
        double lg[NEXP], mx = -1e300;
#pragma unroll
        for (int e = 0; e < NEXP; ++e) { lg[e] = acc[e] + (double)bg[e]; mx = lg[e] > mx ? lg[e] : mx; }
        double p[NEXP], s = 0.0;
#pragma unroll
        for (int e = 0; e < NEXP; ++e) { p[e] = exp(lg[e] - mx); s += p[e]; }
#pragma unroll
        for (int e = 0; e < NEXP; ++e) p[e] /= s;
        int i0 = 0;
#pragma unroll
        for (int e = 1; e < NEXP; ++e) if (p[e] > p[i0]) i0 = e;
        int i1 = (i0 == 0) ? 1 : 0;
#pragma unroll
        for (int e = 0; e < NEXP; ++e) if (e != i0 && p[e] > p[i1]) i1 = e;
        out_idx[t * 2 + 0] = (float)i0;
        out_idx[t * 2 + 1] = (float)i1;
        out_val[t * 2 + 0] = (float)p[i0];
        out_val[t * 2 + 1] = (float)p[i1];
        tok_e[t * 2 + 0] = i0; tok_e[t * 2 + 1] = i1;
        tok_g[t * 2 + 0] = (float)p[i0]; tok_g[t * 2 + 1] = (float)p[i1];
        atomicAdd(&cnt[i0], 1);
        atomicAdd(&cnt[i1], 1);
    }
}

// ---------------- 128-padded segment offsets ---------------------------------
__global__ void offsets_kernel(const int* __restrict__ cnt, int* __restrict__ off_pad) {
    if (threadIdx.x == 0 && blockIdx.x == 0) {
        int o = 0;
        off_pad[0] = 0;
#pragma unroll
        for (int e = 0; e < NEXP; ++e) {
            o += ((cnt[e] + 127) >> 7) << 7;
            off_pad[e + 1] = o;
        }
    }
}

// ---------------- scatter tokens into padded row space -----------------------
__global__ void scatter_kernel(const int* __restrict__ tok_e, const float* __restrict__ tok_g,
                               const int* __restrict__ off_pad, int* __restrict__ fill,
                               int* __restrict__ row_token, float* __restrict__ row_gate) {
    int i = blockIdx.x * blockDim.x + threadIdx.x;
    if (i < T_TOK * TOPK) {
        int e = tok_e[i];
        int pos = off_pad[e] + atomicAdd(&fill[e], 1);
        row_token[pos] = i >> 1;
        row_gate[pos] = tok_g[i];
    }
}

// ---------------- grouped GEMM: double-buffered BK=32, XOR swizzle -----------
// C = A * W^T. LDS: 2 bufs x (128 A-rows + 128 B-rows) x 32 cols bf16 = 32 KB
// (same footprint as the R2 single-buffer BK=64 -> occupancy unchanged).
// Loads for iter k+1 issue right after iter k's barrier, so the vmcnt(0)
// drain at iter k+1's barrier finds them ~1 iteration old (latency hiding).
// Swizzle: physical chunk = logical chunk ^ ((row>>1)&3); keeps ds_read_b128
// at the bank floor (verified 0 conflicts with the R2 variant of this trick).
// MODE 0: A = gathered x_bf16 rows, store h = leakyrelu(C + b1) as bf16
// MODE 1: A = h rows, atomicAdd gate*(C + b2) into out
template <int MODE, int KD, int ND>
__global__ __launch_bounds__(256)
void moe_gemm(const unsigned short* __restrict__ A, const unsigned short* __restrict__ W,
              const float* __restrict__ bias, const int* __restrict__ row_token,
              const float* __restrict__ row_gate, const int* __restrict__ off_pad,
              const unsigned short* __restrict__ zero_row,
              unsigned short* __restrict__ Hout, float* __restrict__ Out) {
    __shared__ unsigned short As[2 * 128 * 32];
    __shared__ unsigned short Bs[2 * 128 * 32];
    const int m0 = blockIdx.x * 128;
    const int n0 = blockIdx.y * 128;
    // expert for this row tile (off_pad monotone; last true wins)
    int e = 0;
#pragma unroll
    for (int q = 0; q < NEXP - 1; ++q)
        if (off_pad[q + 1] <= m0) e = q + 1;

    const int tid = threadIdx.x;
    const int wave = tid >> 6;
    const int lane = tid & 63;
    const int wm = wave >> 1, wn = wave & 1;
    const int lane15 = lane & 15;
    const int quad = lane >> 4;

    // staging geometry: 128 rows x 4 chunks (16B) per matrix = 512 chunks,
    // 2 rounds of 256 threads. row = r*64 + (tid>>2), logical chunk = tid&3.
    const int col4 = tid & 3;
    const int sswz = (tid >> 3) & 3;       // (row>>1)&3, r-invariant
    const int scol = col4 ^ sswz;          // swizzled source chunk

    const unsigned short* aptr[2];
    const unsigned short* bptr[2];
#pragma unroll
    for (int r = 0; r < 2; ++r) {
        int row = r * 64 + (tid >> 2);
        const unsigned short* ab;
        if (MODE == 0) {
            int tok = row_token[m0 + row];
            ab = (tok < 0) ? zero_row : (A + (size_t)tok * KD);
        } else {
            ab = A + (size_t)(m0 + row) * KD;
        }
        aptr[r] = ab + scol * 8;
        bptr[r] = W + ((size_t)e * ND + (size_t)(n0 + row)) * (size_t)KD + scol * 8;
    }

    f32x4 acc[4][4];
#pragma unroll
    for (int i = 0; i < 4; ++i)
#pragma unroll
        for (int j = 0; j < 4; ++j) acc[i][j] = (f32x4)0.f;

    const int rowA = wm * 64 + lane15;     // + i*16 per fragment
    const int rowB = wn * 64 + lane15;     // + j*16 per fragment
    const int pcs = ((quad ^ ((lane15 >> 1) & 3)) * 8);  // physical chunk offset (shorts)

    // prologue: stage k0=0 into buffer 0
#pragma unroll
    for (int r = 0; r < 2; ++r) {
        __builtin_amdgcn_global_load_lds(
            (const __attribute__((address_space(1))) void*)(aptr[r]),
            (__attribute__((address_space(3))) void*)(As + (r * 256 + wave * 64) * 8), 16, 0, 0);
        __builtin_amdgcn_global_load_lds(
            (const __attribute__((address_space(1))) void*)(bptr[r]),
            (__attribute__((address_space(3))) void*)(Bs + (r * 256 + wave * 64) * 8), 16, 0, 0);
    }

    int buf = 0;
    for (int k0 = 0; k0 < KD; k0 += 32) {
        __syncthreads();               // drains this iter's staged loads
        const int nbuf = buf ^ 1;
        if (k0 + 32 < KD) {            // stage next tile into the other buffer
#pragma unroll
            for (int r = 0; r < 2; ++r) {
                __builtin_amdgcn_global_load_lds(
                    (const __attribute__((address_space(1))) void*)(aptr[r] + k0 + 32),
                    (__attribute__((address_space(3))) void*)(As + nbuf * 4096 + (r * 256 + wave * 64) * 8), 16, 0, 0);
                __builtin_amdgcn_global_load_lds(
                    (const __attribute__((address_space(1))) void*)(bptr[r] + k0 + 32),
                    (__attribute__((address_space(3))) void*)(Bs + nbuf * 4096 + (r * 256 + wave * 64) * 8), 16, 0, 0);
            }
        }
        bf16x8 af[4], bfv[4];
#pragma unroll
        for (int i = 0; i < 4; ++i)
            af[i] = *(const bf16x8*)(As + buf * 4096 + (rowA + i * 16) * 32 + pcs);
#pragma unroll
        for (int j = 0; j < 4; ++j)
            bfv[j] = *(const bf16x8*)(Bs + buf * 4096 + (rowB + j * 16) * 32 + pcs);
#pragma unroll
        for (int i = 0; i < 4; ++i)
#pragma unroll
            for (int j = 0; j < 4; ++j)
                acc[i][j] = __builtin_amdgcn_mfma_f32_16x16x32_bf16(af[i], bfv[j], acc[i][j], 0, 0, 0);
        buf = nbuf;
    }

    // epilogue
    float bv[4];
#pragma unroll
    for (int j = 0; j < 4; ++j)
        bv[j] = bias[e * ND + n0 + wn * 64 + j * 16 + lane15];
#pragma unroll
    for (int i = 0; i < 4; ++i) {
#pragma unroll
        for (int r4 = 0; r4 < 4; ++r4) {
            int m = m0 + wm * 64 + i * 16 + quad * 4 + r4;
            int tok = 0; float g = 0.f;
            if (MODE == 1) { tok = row_token[m]; g = row_gate[m]; }
#pragma unroll
            for (int j = 0; j < 4; ++j) {
                int n = n0 + wn * 64 + j * 16 + lane15;
                float v = acc[i][j][r4] + bv[j];
                if (MODE == 0) {
                    v = v > 0.f ? v : 0.1f * v;
                    Hout[(size_t)m * ND + n] = f2bf(v);
                } else {
                    if (tok >= 0) atomicAdd(Out + (size_t)tok * ND + n, g * v);
                }
            }
        }
    }
}

extern "C" void kernel_launch(void* const* d_in, const int* in_sizes, int n_in,
                              void* d_out, int out_size, void* d_ws, size_t ws_size,
                              hipStream_t stream) {
    const float* x  = (const float*)d_in[0];
    const float* wg = (const float*)d_in[1];
    const float* bg = (const float*)d_in[2];
    const float* w1 = (const float*)d_in[3];
    const float* b1 = (const float*)d_in[4];
    const float* w2 = (const float*)d_in[5];
    const float* b2 = (const float*)d_in[6];
    float* out0 = (float*)d_out;
    float* out_idx = out0 + (size_t)T_TOK * DMODEL;
    float* out_val = out_idx + T_TOK * TOPK;

    char* p = (char*)d_ws;
    auto alloc = [&](size_t bytes) {
        char* q = p;
        p += (bytes + 255) & ~(size_t)255;
        return q;
    };
    unsigned short* xb  = (unsigned short*)alloc((size_t)T_TOK * DMODEL * 2);
    unsigned short* w1b = (unsigned short*)alloc((size_t)NEXP * FFDIM * DMODEL * 2);
    unsigned short* w2b = (unsigned short*)alloc((size_t)NEXP * DMODEL * FFDIM * 2);
    unsigned short* hb  = (unsigned short*)alloc((size_t)ROWS_PAD * FFDIM * 2);
    unsigned short* zrow = (unsigned short*)alloc(DMODEL * 2);
    int* cnt = (int*)alloc(64);   // cnt[8] + fill[8]
    int* fill = cnt + 8;
    int* off_pad = (int*)alloc(64);
    int* tok_e = (int*)alloc((size_t)T_TOK * TOPK * 4);
    float* tok_g = (float*)alloc((size_t)T_TOK * TOPK * 4);
    int* row_token = (int*)alloc((size_t)ROWS_PAD * 4);
    float* row_gate = (float*)alloc((size_t)ROWS_PAD * 4);
    if ((size_t)(p - (char*)d_ws) > ws_size) return;  // ws too small: fail visibly, no OOB

    init_kernel<<<(T_TOK * DMODEL + 255) / 256, 256, 0, stream>>>(out0, row_token, zrow, cnt);
    cvt_kernel<<<(T_TOK * DMODEL / 4 + 255) / 256, 256, 0, stream>>>(x, xb, T_TOK * DMODEL / 4);
    cvt_kernel<<<(NEXP * FFDIM * DMODEL / 4 + 255) / 256, 256, 0, stream>>>(w1, w1b, NEXP * FFDIM * DMODEL / 4);
    cvt_kernel<<<(NEXP * DMODEL * FFDIM / 4 + 255) / 256, 256, 0, stream>>>(w2, w2b, NEXP * DMODEL * FFDIM / 4);
    gate_kernel<<<T_TOK / 4, 256, 0, stream>>>(x, wg, bg, out_idx, out_val, tok_e, tok_g, cnt);
    offsets_kernel<<<1, 64, 0, stream>>>(cnt, off_pad);
    scatter_kernel<<<(T_TOK * TOPK + 255) / 256, 256, 0, stream>>>(tok_e, tok_g, off_pad, fill, row_token, row_gate);
    moe_gemm<0, DMODEL, FFDIM><<<dim3(MTILES, FFDIM / 128), 256, 0, stream>>>(
        xb, w1b, b1, row_token, row_gate, off_pad, zrow, hb, nullptr);
    moe_gemm<1, FFDIM, DMODEL><<<dim3(MTILES, DMODEL / 128), 256, 0, stream>>>(
        hb, w2b, b2, row_token, row_gate, off_pad, zrow, nullptr, out0);
}